// Round 3
// baseline (47932.318 us; speedup 1.0000x reference)
//
#include <hip/hip_runtime.h>

// RNNModel: 2-layer LSTM (B=64,T=400,E=H=500) + MLP head (800->100->2).
// Round 3: zero-duplication weight-stationary VGPRs.
//  - 256 blocks (1/CU), persistent, grid barrier per step (401 steps, layers pipelined).
//  - Layer L = bid>>7; lid = bid&127; active lid<125. Block owns 16 cols
//    (4 units x 4 gates) x full K=1000 for ALL 64 batches (2 passes of 32).
//  - Threads: wave w=tid>>6 owns K-chunk [128w,128w+128) (K padded 1000->1024 with
//    zero weights + zeroed LDS rows); lane = cp*8+ks: cp=col-pair, ks=k mod 8.
//    Per-thread weights: 2 cols x 16 k = 32 floats in VGPRs (static unrolls only).
//  - x staged transposed in LDS [k][32b], XOR-quad swizzle (quad ^= k&7):
//    K-loop b128 reads are conflict-free (ks spans 8 distinct quads).
//  - f32 16-term serial per thread, f32 shfl_xor tree over ks (3 rounds),
//    8 chunk partials combined in f64 + f64 gates/cell (round-1 numerics family).

#define NBLK 256
#define NTHR 512
#define Bn 64
#define Tn 400
#define Hn 500

// ws byte offsets
#define OFF_H1 0            // float [2][64*500]
#define OFF_H2 256000       // float [2][64*500]
#define OFF_D1 512000       // float [64*800]
#define OFF_D2 716800       // float [64*100]
#define OFF_CNT 742400      // unsigned counter

__device__ __forceinline__ void gbar(unsigned* cnt, unsigned target) {
    __syncthreads();
    if (threadIdx.x == 0) {
        __threadfence();
        unsigned prevv = __hip_atomic_fetch_add(cnt, 1u, __ATOMIC_ACQ_REL,
                                                __HIP_MEMORY_SCOPE_AGENT);
        if (prevv + 1u != target) {
            while (__hip_atomic_load(cnt, __ATOMIC_ACQUIRE,
                                     __HIP_MEMORY_SCOPE_AGENT) < target) {
                __builtin_amdgcn_s_sleep(2);
            }
        }
    }
    __syncthreads();
}

extern "C" __global__ void __launch_bounds__(NTHR, 2)
rnn_all(const int* __restrict__ X, const float* __restrict__ embed,
        const float* __restrict__ k1, const float* __restrict__ b1,
        const float* __restrict__ k2, const float* __restrict__ b2,
        const float* __restrict__ w1, const float* __restrict__ bw1,
        const float* __restrict__ w2, const float* __restrict__ bw2,
        const float* __restrict__ wpm, const float* __restrict__ bpv,
        float* __restrict__ out, char* __restrict__ ws)
{
    __shared__ float s_x[32768];   // [k<1024][b32], quad-swizzled: 128 KB
    __shared__ float s_P[4096];    // [w8][c16][b32] chunk partials: 16 KB

    float* h1b = (float*)(ws + OFF_H1);
    float* h2b = (float*)(ws + OFF_H2);
    float* d1p = (float*)(ws + OFF_D1);
    float* d2p = (float*)(ws + OFF_D2);
    unsigned* cnt = (unsigned*)(ws + OFF_CNT);

    const int bid = blockIdx.x;
    const int tid = threadIdx.x;
    const int L = bid >> 7;
    const int lid = bid & 127;
    const bool ablk = (lid < 125);
    const int ut = lid;                 // unit tile: units ut*4..ut*4+3
    const int w = tid >> 6;             // wave = K chunk of 128
    const int lane = tid & 63;
    const int cp = lane >> 3;           // col pair 0..7
    const int ks = lane & 7;            // k mod 8 within chunk

    const float* Wm = L ? k2 : k1;      // [1000][2000] cols = g*500+u
    const float* bv = L ? b2 : b1;

    // ---- one-time: zero pad rows k=1000..1023 ----
    for (int idx = tid; idx < 768; idx += NTHR) s_x[32000 + idx] = 0.f;

    // ---- one-time weight preload: wreg[2][16] ----
    float wr0[16], wr1[16];
    {
        const int c0 = 2 * cp, c1 = 2 * cp + 1;
        const int col0 = (c0 >> 2) * 500 + ut * 4 + (c0 & 3);
        const int col1 = (c1 >> 2) * 500 + ut * 4 + (c1 & 3);
        #pragma unroll
        for (int i = 0; i < 16; ++i) {
            const int k = 128 * w + 8 * i + ks;
            const bool ok = ablk && (k < 1000);
            wr0[i] = ok ? Wm[(size_t)k * 2000 + col0] : 0.f;
            wr1[i] = ok ? Wm[(size_t)k * 2000 + col1] : 0.f;
        }
    }

    // ---- gate-thread init (tid<128): owns unit u, batch bL per pass ----
    const int bL = tid >> 2;            // 0..31 (for tid<128)
    const int uu4 = tid & 3;
    const int u = ut * 4 + uu4;
    const bool gth = ablk && (tid < 128);
    float bias_g[4];
    #pragma unroll
    for (int g = 0; g < 4; ++g) bias_g[g] = gth ? bv[g * 500 + u] : 0.f;
    double cs0 = 0.0, cs1 = 0.0;        // cell state for pass0/pass1 batch

    // staging constants (pass-invariant)
    const int sb_full = tid & 31;       // stage (512 thr): batch lane
    const int skq_full = tid >> 5;      // kq base, step 16
    const int sb_part = (tid - 128) & 31;   // stage (384 thr)
    const int skq_part = (tid - 128) >> 5;  // kq base, step 12

    unsigned ep = 0;

    for (int s = 0; s <= Tn; ++s) {
        const int cur = s & 1;
        const int prv = cur ^ 1;
        const float* h1prev = h1b + prv * 32000;
        const float* h2prev = h2b + prv * 32000;
        float* hout = (L ? h2b : h1b) + cur * 32000;
        const bool active = ablk && (L ? (s >= 1) : (s < Tn));

        if (active) {
            const int t = L ? (s - 1) : s;

            // ================== PASS 0 (batches 0..31) ==================
            {   // stage x for b 0..31 (all 512 threads)
                const int b = sb_full;
                const float* rowA;
                const float* rowB;
                if (L == 0) {
                    rowA = embed + (size_t)X[b * Tn + t] * 500;
                    rowB = h1prev + b * 500;
                } else {
                    rowA = h1prev + b * 500;
                    rowB = h2prev + b * 500;
                }
                #pragma unroll
                for (int j = 0; j < 16; ++j) {
                    const int kq = skq_full + 16 * j;
                    if (kq < 250) {
                        const int k = 4 * kq;
                        const float4 v = (k < 500) ? *(const float4*)(rowA + k)
                                                   : *(const float4*)(rowB + (k - 500));
                        const int bq = b >> 2, br = b & 3;
                        s_x[(k+0)*32 + (((bq) ^ ((k+0)&7))<<2) + br] = v.x;
                        s_x[(k+1)*32 + (((bq) ^ ((k+1)&7))<<2) + br] = v.y;
                        s_x[(k+2)*32 + (((bq) ^ ((k+2)&7))<<2) + br] = v.z;
                        s_x[(k+3)*32 + (((bq) ^ ((k+3)&7))<<2) + br] = v.w;
                    }
                }
            }
            __syncthreads();
            {   // K-loop pass 0
                float4 a0[8], a1[8];
                #pragma unroll
                for (int q = 0; q < 8; ++q) { a0[q] = make_float4(0,0,0,0); a1[q] = make_float4(0,0,0,0); }
                #pragma unroll
                for (int i = 0; i < 16; ++i) {
                    const int kk = 128 * w + 8 * i + ks;
                    const float* xr = s_x + kk * 32;
                    const float w0 = wr0[i], w1v = wr1[i];
                    #pragma unroll
                    for (int q = 0; q < 8; ++q) {
                        const float4 xv = *(const float4*)(xr + ((q ^ ks) << 2));
                        a0[q].x = fmaf(w0, xv.x, a0[q].x);
                        a0[q].y = fmaf(w0, xv.y, a0[q].y);
                        a0[q].z = fmaf(w0, xv.z, a0[q].z);
                        a0[q].w = fmaf(w0, xv.w, a0[q].w);
                        a1[q].x = fmaf(w1v, xv.x, a1[q].x);
                        a1[q].y = fmaf(w1v, xv.y, a1[q].y);
                        a1[q].z = fmaf(w1v, xv.z, a1[q].z);
                        a1[q].w = fmaf(w1v, xv.w, a1[q].w);
                    }
                }
                // shfl_xor tree over ks (1,2,4), then ks==0 writes s_P
                #pragma unroll
                for (int q = 0; q < 8; ++q) {
                    #pragma unroll
                    for (int m = 1; m <= 4; m <<= 1) {
                        a0[q].x += __shfl_xor(a0[q].x, m, 64);
                        a0[q].y += __shfl_xor(a0[q].y, m, 64);
                        a0[q].z += __shfl_xor(a0[q].z, m, 64);
                        a0[q].w += __shfl_xor(a0[q].w, m, 64);
                        a1[q].x += __shfl_xor(a1[q].x, m, 64);
                        a1[q].y += __shfl_xor(a1[q].y, m, 64);
                        a1[q].z += __shfl_xor(a1[q].z, m, 64);
                        a1[q].w += __shfl_xor(a1[q].w, m, 64);
                    }
                }
                if (ks == 0) {
                    const int c0 = 2 * cp, c1 = c0 + 1;
                    #pragma unroll
                    for (int q = 0; q < 8; ++q) {
                        *(float4*)&s_P[w*512 + c0*32 + ((q ^ (c0 & 7)) << 2)] = a0[q];
                        *(float4*)&s_P[w*512 + c1*32 + ((q ^ (c1 & 7)) << 2)] = a1[q];
                    }
                }
            }
            __syncthreads();
            // ===== gates pass 0 (t<128)  ||  stage pass 1 (t>=128) =====
            if (tid < 128) {
                if (gth) {
                    double z[4];
                    #pragma unroll
                    for (int g = 0; g < 4; ++g) {
                        const int c = g * 4 + uu4;
                        const int off = c * 32 + (((bL >> 2) ^ (c & 7)) << 2) + (bL & 3);
                        double zz = 0.0;
                        #pragma unroll
                        for (int q = 0; q < 8; ++q) zz += (double)s_P[q * 512 + off];
                        z[g] = zz + (double)bias_g[g];
                    }
                    const double gi = 1.0 / (1.0 + exp(-z[0]));
                    const double gf = 1.0 / (1.0 + exp(-(z[2] + 1.0)));
                    const double go = 1.0 / (1.0 + exp(-z[3]));
                    cs0 = gf * cs0 + gi * tanh(z[1]);
                    hout[bL * 500 + u] = (float)(go * tanh(cs0));
                }
            } else {
                const int b = sb_part;          // batch 32+b
                const float* rowA;
                const float* rowB;
                if (L == 0) {
                    rowA = embed + (size_t)X[(32 + b) * Tn + t] * 500;
                    rowB = h1prev + (32 + b) * 500;
                } else {
                    rowA = h1prev + (32 + b) * 500;
                    rowB = h2prev + (32 + b) * 500;
                }
                #pragma unroll
                for (int j = 0; j < 21; ++j) {
                    const int kq = skq_part + 12 * j;
                    if (kq < 250) {
                        const int k = 4 * kq;
                        const float4 v = (k < 500) ? *(const float4*)(rowA + k)
                                                   : *(const float4*)(rowB + (k - 500));
                        const int bq = b >> 2, br = b & 3;
                        s_x[(k+0)*32 + (((bq) ^ ((k+0)&7))<<2) + br] = v.x;
                        s_x[(k+1)*32 + (((bq) ^ ((k+1)&7))<<2) + br] = v.y;
                        s_x[(k+2)*32 + (((bq) ^ ((k+2)&7))<<2) + br] = v.z;
                        s_x[(k+3)*32 + (((bq) ^ ((k+3)&7))<<2) + br] = v.w;
                    }
                }
            }
            __syncthreads();
            {   // K-loop pass 1 (batches 32..63)
                float4 a0[8], a1[8];
                #pragma unroll
                for (int q = 0; q < 8; ++q) { a0[q] = make_float4(0,0,0,0); a1[q] = make_float4(0,0,0,0); }
                #pragma unroll
                for (int i = 0; i < 16; ++i) {
                    const int kk = 128 * w + 8 * i + ks;
                    const float* xr = s_x + kk * 32;
                    const float w0 = wr0[i], w1v = wr1[i];
                    #pragma unroll
                    for (int q = 0; q < 8; ++q) {
                        const float4 xv = *(const float4*)(xr + ((q ^ ks) << 2));
                        a0[q].x = fmaf(w0, xv.x, a0[q].x);
                        a0[q].y = fmaf(w0, xv.y, a0[q].y);
                        a0[q].z = fmaf(w0, xv.z, a0[q].z);
                        a0[q].w = fmaf(w0, xv.w, a0[q].w);
                        a1[q].x = fmaf(w1v, xv.x, a1[q].x);
                        a1[q].y = fmaf(w1v, xv.y, a1[q].y);
                        a1[q].z = fmaf(w1v, xv.z, a1[q].z);
                        a1[q].w = fmaf(w1v, xv.w, a1[q].w);
                    }
                }
                #pragma unroll
                for (int q = 0; q < 8; ++q) {
                    #pragma unroll
                    for (int m = 1; m <= 4; m <<= 1) {
                        a0[q].x += __shfl_xor(a0[q].x, m, 64);
                        a0[q].y += __shfl_xor(a0[q].y, m, 64);
                        a0[q].z += __shfl_xor(a0[q].z, m, 64);
                        a0[q].w += __shfl_xor(a0[q].w, m, 64);
                        a1[q].x += __shfl_xor(a1[q].x, m, 64);
                        a1[q].y += __shfl_xor(a1[q].y, m, 64);
                        a1[q].z += __shfl_xor(a1[q].z, m, 64);
                        a1[q].w += __shfl_xor(a1[q].w, m, 64);
                    }
                }
                if (ks == 0) {
                    const int c0 = 2 * cp, c1 = c0 + 1;
                    #pragma unroll
                    for (int q = 0; q < 8; ++q) {
                        *(float4*)&s_P[w*512 + c0*32 + ((q ^ (c0 & 7)) << 2)] = a0[q];
                        *(float4*)&s_P[w*512 + c1*32 + ((q ^ (c1 & 7)) << 2)] = a1[q];
                    }
                }
            }
            __syncthreads();
            if (gth) {  // gates pass 1
                double z[4];
                #pragma unroll
                for (int g = 0; g < 4; ++g) {
                    const int c = g * 4 + uu4;
                    const int off = c * 32 + (((bL >> 2) ^ (c & 7)) << 2) + (bL & 3);
                    double zz = 0.0;
                    #pragma unroll
                    for (int q = 0; q < 8; ++q) zz += (double)s_P[q * 512 + off];
                    z[g] = zz + (double)bias_g[g];
                }
                const double gi = 1.0 / (1.0 + exp(-z[0]));
                const double gf = 1.0 / (1.0 + exp(-(z[2] + 1.0)));
                const double go = 1.0 / (1.0 + exp(-z[3]));
                cs1 = gf * cs1 + gi * tanh(z[1]);
                hout[(32 + bL) * 500 + u] = (float)(go * tanh(cs1));
            }
        }
        ++ep;
        gbar(cnt, ep * NBLK);
    }

    // ---- dense head (f64 accumulation), validated in round 1 ----
    const float* last = h2b + (Tn & 1) * 32000;
    if (tid < 200) {
        int o = bid * 200 + tid;                  // 256*200 = 64*800
        int b = o / 800, j = o - b * 800;
        const float* lr = last + b * 500;
        double acc = 0;
        for (int kk = 0; kk < 500; ++kk)
            acc += (double)lr[kk] * (double)w1[(size_t)kk * 800 + j];
        acc += (double)bw1[j];
        d1p[b * 800 + j] = (float)fmax(acc, 0.0);
    }
    ++ep;
    gbar(cnt, ep * NBLK);
    if (tid < 25) {
        int o = bid * 25 + tid;                   // 256*25 = 64*100
        int b = o / 100, j = o - b * 100;
        const float* dr = d1p + b * 800;
        double acc = 0;
        for (int kk = 0; kk < 800; ++kk)
            acc += (double)dr[kk] * (double)w2[(size_t)kk * 100 + j];
        acc += (double)bw2[j];
        d2p[b * 100 + j] = (float)fmax(acc, 0.0);
    }
    ++ep;
    gbar(cnt, ep * NBLK);
    if (bid == 0 && tid < 128) {
        int b = tid >> 1, cc = tid & 1;
        const float* dr = d2p + b * 100;
        double acc = 0;
        for (int kk = 0; kk < 100; ++kk)
            acc += (double)dr[kk] * (double)wpm[kk * 2 + cc];
        acc += (double)bpv[cc];
        out[b * 2 + cc] = (float)acc;
    }
}

extern "C" void kernel_launch(void* const* d_in, const int* in_sizes, int n_in,
                              void* d_out, int out_size, void* d_ws, size_t ws_size,
                              hipStream_t stream) {
    const int* X = (const int*)d_in[0];
    const float* embed = (const float*)d_in[1];
    const float* k1 = (const float*)d_in[2];
    const float* b1 = (const float*)d_in[3];
    const float* k2 = (const float*)d_in[4];
    const float* b2 = (const float*)d_in[5];
    const float* w1 = (const float*)d_in[6];
    const float* bw1 = (const float*)d_in[7];
    const float* w2 = (const float*)d_in[8];
    const float* bw2 = (const float*)d_in[9];
    const float* wpm = (const float*)d_in[10];
    const float* bpv = (const float*)d_in[11];

    hipMemsetAsync(d_ws, 0, 512000, stream);
    hipMemsetAsync((char*)d_ws + OFF_CNT, 0, 64, stream);

    rnn_all<<<NBLK, NTHR, 0, stream>>>(X, embed, k1, b1, k2, b2, w1, bw1,
                                       w2, bw2, wpm, bpv,
                                       (float*)d_out, (char*)d_ws);
}

// Round 4
// 21386.307 us; speedup vs baseline: 2.2413x; 2.2413x over previous
//
#include <hip/hip_runtime.h>

// RNNModel: 2-layer LSTM (B=64,T=400,E=H=500) + MLP head (800->100->2).
// Round 4: L2-resident weights streamed L2->LDS (global_load_lds, dbuf),
// XCD-swizzled block map, flag/broadcast grid barrier, low-VGPR compute.
//  - 256 blocks (1/CU) persistent; grid-step s: L0 computes t=s, L1 t=s-1.
//  - block = (L, btile of 16 batches, ut of 16 units); slice = (L,ut) weights
//    [1000 x 64 cols]; 4 btile-duplicates of a slice share an XCD (bid&7).
//  - per chunk (128 k-rows): stage next chunk via global_load_lds while
//    computing current from LDS; wave w owns rows w*16..; lane = (cq,bp):
//    4 cols x 4 batches outer product, acc[4][4] f32.
//  - h stored transposed [500][64] in ws so x staging is linear gll.
//  - numerics: f32 serial per-thread partials, f64 combine over 8 waves,
//    f64 gates/cell, f32 h, f64 head (family measured absmax 0.0).

#define NBLK 256
#define NTHR 512
#define Bn 64
#define Tn 400
#define Hn 500

#define OFF_H1  0            // float [2][500*64] transposed h1
#define OFF_H2  256000       // float [2][500*64] transposed h2
#define OFF_D1  512000       // float [64*800]
#define OFF_D2  716800       // float [64*100]
#define OFF_FLG 742400       // 256 flags, stride 64 B
#define OFF_GO  758784       // broadcast epoch

__device__ __forceinline__ void gbar(unsigned* flags, unsigned* gop,
                                     int bid, int tid, unsigned ep) {
    __syncthreads();
    if (bid == 0) {
        if (tid >= 1 && tid < NBLK) {
            while (__hip_atomic_load(&flags[tid * 16], __ATOMIC_ACQUIRE,
                                     __HIP_MEMORY_SCOPE_AGENT) < ep)
                __builtin_amdgcn_s_sleep(1);
        }
        __syncthreads();
        if (tid == 0) {
            __threadfence();
            __hip_atomic_store(gop, ep, __ATOMIC_RELEASE, __HIP_MEMORY_SCOPE_AGENT);
        }
    } else {
        if (tid == 0) {
            __threadfence();
            __hip_atomic_store(&flags[bid * 16], ep, __ATOMIC_RELEASE,
                               __HIP_MEMORY_SCOPE_AGENT);
            while (__hip_atomic_load(gop, __ATOMIC_ACQUIRE,
                                     __HIP_MEMORY_SCOPE_AGENT) < ep)
                __builtin_amdgcn_s_sleep(1);
        }
        __syncthreads();
    }
}

extern "C" __global__ void __launch_bounds__(NTHR)
rnn_all(const int* __restrict__ X, const float* __restrict__ embed,
        const float* __restrict__ k1, const float* __restrict__ b1,
        const float* __restrict__ k2, const float* __restrict__ b2,
        const float* __restrict__ w1, const float* __restrict__ bw1,
        const float* __restrict__ w2, const float* __restrict__ bw2,
        const float* __restrict__ wpm, const float* __restrict__ bpv,
        float* __restrict__ out, char* __restrict__ ws)
{
    __shared__ float s_x[16384];     // [k][16] transposed x (rows 0..1023)
    __shared__ float s_w[2][8192];   // dbuf [128 rows][64 cols]
    // s_P alias: s_x floats [0, 8192) = [w8][col64][b16], used post-compute

    float* h1b = (float*)(ws + OFF_H1);
    float* h2b = (float*)(ws + OFF_H2);
    float* d1p = (float*)(ws + OFF_D1);
    float* d2p = (float*)(ws + OFF_D2);
    unsigned* flags = (unsigned*)(ws + OFF_FLG);
    unsigned* gop = (unsigned*)(ws + OFF_GO);

    const int bid = blockIdx.x;
    const int tid = threadIdx.x;
    // XCD-swizzle: 4 btile-duplicates of slice share bid&7 (presumed XCD)
    const int rr_ = bid >> 3;
    const int slice = (bid & 7) * 8 + (rr_ >> 2);  // 0..63
    const int btile = rr_ & 3;
    const int L = slice >> 5;
    const int ut = slice & 31;
    const int b0 = btile * 16;

    const int w = tid >> 6;          // wave
    const int l = tid & 63;
    const int cq = l & 15;           // col quad (4 cols)
    const int bp = l >> 4;           // batch quad (4 batches)

    const float* Wm = L ? k2 : k1;   // [1000][2000], col = g*500+u
    const float* bv = L ? b2 : b1;

    // weight-stage lane constants (col-quad cq covers local cols 4cq..4cq+3)
    const int wg = cq >> 2;
    const int wcol = wg * 500 + min(ut * 16 + 4 * (cq & 3), 496);
    const int wri = l >> 4;          // row within a 4-row inst

    // x-stage lane constants
    const int xr4 = l >> 2;
    const int xj = (l & 3) * 4;

    // gate thread constants (tid<256): (batch gb, unit uu)
    const int uu = tid & 15;
    const int gb = tid >> 4;
    const int u = ut * 16 + uu;
    const bool gth = (tid < 256) && (u < Hn);
    const float bg0 = gth ? bv[u] : 0.f;
    const float bg1 = gth ? bv[500 + u] : 0.f;
    const float bg2 = gth ? bv[1000 + u] : 0.f;
    const float bg3 = gth ? bv[1500 + u] : 0.f;
    double cstate = 0.0;

    unsigned ep = 0;

    for (int s = 0; s <= Tn; ++s) {
        const int cur = s & 1, prv = cur ^ 1;
        const float* h1p = h1b + prv * 32000;
        const float* h2p = h2b + prv * 32000;
        float* houtT = (L ? h2b : h1b) + cur * 32000;
        const bool active = L ? (s >= 1) : (s < Tn);

        if (active) {
            const int t = L ? (s - 1) : s;
            // ---------- x staging (rows transposed [k][16]) ----------
            if (L == 0) {
                #pragma unroll
                for (int q = 0; q < 4; ++q) {   // h1prev -> rows 500.. (linear)
                    const int m = w * 4 + q;
                    const float* src = h1p + (m * 16 + xr4) * 64 + b0 + xj;
                    __builtin_amdgcn_global_load_lds(src, &s_x[8000 + m * 256], 16, 0, 0);
                }
                const int eb = tid & 15;        // embed transpose rows 0..499
                const int q0 = tid >> 4;
                const float* er = embed + (size_t)X[(b0 + eb) * Tn + t] * 500;
                #pragma unroll
                for (int jj = 0; jj < 4; ++jj) {
                    const int q = q0 + 32 * jj;
                    if (q < 125) {
                        const float4 v = *(const float4*)(er + 4 * q);
                        float* d = &s_x[(4 * q) * 16 + eb];
                        d[0] = v.x; d[16] = v.y; d[32] = v.z; d[48] = v.w;
                    }
                }
            } else {
                #pragma unroll
                for (int q = 0; q < 8; ++q) {
                    const int m = w * 8 + q;
                    const int k = m * 16 + xr4;
                    const float* src = (k < 500) ? (h1p + k * 64 + b0 + xj)
                                                 : (h2p + (k - 500) * 64 + b0 + xj);
                    __builtin_amdgcn_global_load_lds(src, &s_x[m * 256], 16, 0, 0);
                }
            }
            // ---------- weight chunk 0 ----------
            #pragma unroll
            for (int q = 0; q < 4; ++q) {
                const int m = w * 4 + q;
                const float* src = Wm + (size_t)(4 * m + wri) * 2000 + wcol;
                __builtin_amdgcn_global_load_lds(src, &s_w[0][m * 256], 16, 0, 0);
            }
            __syncthreads();

            float acc[4][4];
            #pragma unroll
            for (int a_ = 0; a_ < 4; ++a_) {
                acc[a_][0] = 0.f; acc[a_][1] = 0.f; acc[a_][2] = 0.f; acc[a_][3] = 0.f;
            }

            for (int c = 0; c < 8; ++c) {
                if (c < 7) {                      // prefetch chunk c+1
                    const int k0n = (c + 1) * 128;
                    const int nrn = (c < 6) ? 128 : 104;
                    #pragma unroll
                    for (int q = 0; q < 4; ++q) {
                        const int m = w * 4 + q;
                        const int rl = min(4 * m + wri, nrn - 1);
                        const float* src = Wm + (size_t)(k0n + rl) * 2000 + wcol;
                        __builtin_amdgcn_global_load_lds(src, &s_w[(c + 1) & 1][m * 256], 16, 0, 0);
                    }
                }
                const int nr = (c < 7) ? 16 : 13;
                const int k0 = (c < 7) ? c * 128 : 896;
                const int r0 = w * nr;
                const float* wp = &s_w[c & 1][r0 * 64 + cq * 4];
                const float* xp = &s_x[(k0 + r0) * 16 + bp * 4];
                #pragma unroll 8
                for (int i = 0; i < nr; ++i) {
                    const float4 wv = *(const float4*)(wp + i * 64);
                    const float4 xv = *(const float4*)(xp + i * 16);
                    acc[0][0] = fmaf(wv.x, xv.x, acc[0][0]);
                    acc[0][1] = fmaf(wv.x, xv.y, acc[0][1]);
                    acc[0][2] = fmaf(wv.x, xv.z, acc[0][2]);
                    acc[0][3] = fmaf(wv.x, xv.w, acc[0][3]);
                    acc[1][0] = fmaf(wv.y, xv.x, acc[1][0]);
                    acc[1][1] = fmaf(wv.y, xv.y, acc[1][1]);
                    acc[1][2] = fmaf(wv.y, xv.z, acc[1][2]);
                    acc[1][3] = fmaf(wv.y, xv.w, acc[1][3]);
                    acc[2][0] = fmaf(wv.z, xv.x, acc[2][0]);
                    acc[2][1] = fmaf(wv.z, xv.y, acc[2][1]);
                    acc[2][2] = fmaf(wv.z, xv.z, acc[2][2]);
                    acc[2][3] = fmaf(wv.z, xv.w, acc[2][3]);
                    acc[3][0] = fmaf(wv.w, xv.x, acc[3][0]);
                    acc[3][1] = fmaf(wv.w, xv.y, acc[3][1]);
                    acc[3][2] = fmaf(wv.w, xv.z, acc[3][2]);
                    acc[3][3] = fmaf(wv.w, xv.w, acc[3][3]);
                }
                __syncthreads();   // also drains chunk c+1 staging (m97 pattern)
            }
            // ---------- partials to s_P (= s_x[0..8192), rows long read) ----------
            #pragma unroll
            for (int ct = 0; ct < 4; ++ct) {
                *(float4*)&s_x[w * 1024 + (4 * cq + ct) * 16 + bp * 4] =
                    make_float4(acc[ct][0], acc[ct][1], acc[ct][2], acc[ct][3]);
            }
            __syncthreads();
            // ---------- gates: f64 combine over 8 waves + LSTM cell ----------
            if (gth) {
                double z0 = 0, z1 = 0, z2 = 0, z3 = 0;
                #pragma unroll
                for (int q = 0; q < 8; ++q) {
                    const int base = q * 1024 + uu * 16 + gb;
                    z0 += (double)s_x[base];
                    z1 += (double)s_x[base + 256];
                    z2 += (double)s_x[base + 512];
                    z3 += (double)s_x[base + 768];
                }
                z0 += (double)bg0; z1 += (double)bg1;
                z2 += (double)bg2; z3 += (double)bg3;
                const double gi = 1.0 / (1.0 + exp(-z0));
                const double gf = 1.0 / (1.0 + exp(-(z2 + 1.0)));
                const double go_ = 1.0 / (1.0 + exp(-z3));
                cstate = gf * cstate + gi * tanh(z1);
                houtT[u * 64 + b0 + gb] = (float)(go_ * tanh(cstate));
            }
        }
        ++ep;
        gbar(flags, gop, bid, tid, ep);
    }

    // ---------- dense head (f64), last h2 = h2b phase 0, transposed ----------
    const float* lastT = h2b;
    if (tid < 200) {
        int o = bid * 200 + tid;                 // 256*200 = 64*800
        int b = o / 800, j = o - b * 800;
        double acci = 0;
        for (int kk = 0; kk < 500; ++kk)
            acci += (double)lastT[kk * 64 + b] * (double)w1[(size_t)kk * 800 + j];
        acci += (double)bw1[j];
        d1p[b * 800 + j] = (float)fmax(acci, 0.0);
    }
    ++ep;
    gbar(flags, gop, bid, tid, ep);
    if (tid < 25) {
        int o = bid * 25 + tid;                  // 256*25 = 64*100
        int b = o / 100, j = o - b * 100;
        const float* dr = d1p + b * 800;
        double acci = 0;
        for (int kk = 0; kk < 800; ++kk)
            acci += (double)dr[kk] * (double)w2[(size_t)kk * 100 + j];
        acci += (double)bw2[j];
        d2p[b * 100 + j] = (float)fmax(acci, 0.0);
    }
    ++ep;
    gbar(flags, gop, bid, tid, ep);
    if (bid == 0 && tid < 128) {
        int b = tid >> 1, cc = tid & 1;
        const float* dr = d2p + b * 100;
        double acci = 0;
        for (int kk = 0; kk < 100; ++kk)
            acci += (double)dr[kk] * (double)wpm[kk * 2 + cc];
        acci += (double)bpv[cc];
        out[b * 2 + cc] = (float)acci;
    }
}

extern "C" void kernel_launch(void* const* d_in, const int* in_sizes, int n_in,
                              void* d_out, int out_size, void* d_ws, size_t ws_size,
                              hipStream_t stream) {
    const int* X = (const int*)d_in[0];
    const float* embed = (const float*)d_in[1];
    const float* k1 = (const float*)d_in[2];
    const float* b1 = (const float*)d_in[3];
    const float* k2 = (const float*)d_in[4];
    const float* b2 = (const float*)d_in[5];
    const float* w1 = (const float*)d_in[6];
    const float* bw1 = (const float*)d_in[7];
    const float* w2 = (const float*)d_in[8];
    const float* bw2 = (const float*)d_in[9];
    const float* wpm = (const float*)d_in[10];
    const float* bpv = (const float*)d_in[11];

    // zero h buffers + barrier flags/go (captured -> clean every replay)
    hipMemsetAsync(d_ws, 0, 512000, stream);
    hipMemsetAsync((char*)d_ws + OFF_FLG, 0, 16448, stream);

    rnn_all<<<NBLK, NTHR, 0, stream>>>(X, embed, k1, b1, k2, b2, w1, bw1,
                                       w2, bw2, wpm, bpv,
                                       (float*)d_out, (char*)d_ws);
}